// Round 13
// baseline (37.427 us; speedup 1.0000x reference)
//
#include <hip/hip_runtime.h>
#include <math.h>

#define FFN_DIM 4096
#define NCHUNK  128        // 4096 / 32
#define CLS     4          // f-classes (chunk-range split across blocks)
#define CCHUNK  (NCHUNK / CLS)   // 32 chunks per class
#define TPB     512        // threads per block = 8 waves
#define TOKB    256        // tokens per block (8 waves x 32)

typedef _Float16 f16x8 __attribute__((ext_vector_type(8)));
typedef __fp16   h16x2 __attribute__((ext_vector_type(2)));
typedef float    f32x16 __attribute__((ext_vector_type(16)));
typedef float    f32x4  __attribute__((ext_vector_type(4)));

// ---------------------------------------------------------------------------
// Pre-kernel: build fp16 MFMA fragment tables in workspace.
//  w1f  [128][64][8] f16 (128KB): lanes 0-31 = W1 rows (k=0..7); lanes 32-63 =
//        {b1, 0,...} so the constant-1 column of q^T adds the bias (k=8).
//  w2f  [128][2][16][8] f16 (64KB): W2 rows permuted so GEMM1's C/D register
//        order feeds GEMM2's B operand directly (verified: absmax 3.9e-3).
// ---------------------------------------------------------------------------
__global__ void build_frags_kernel(const float* __restrict__ w1,
                                   const float* __restrict__ b1,
                                   const float* __restrict__ w2,
                                   _Float16* __restrict__ w1f,
                                   _Float16* __restrict__ w2f) {
    int i = blockIdx.x * 256 + threadIdx.x;
    if (i < NCHUNK * 64 * 8) {              // 65536
        int j    = i & 7;
        int lane = (i >> 3) & 63;
        int cc   = i >> 9;
        _Float16 v;
        if (lane < 32) v = (_Float16)w1[(cc * 32 + lane) * 8 + j];
        else           v = (j == 0) ? (_Float16)b1[cc * 32 + (lane & 31)]
                                    : (_Float16)0.0f;
        w1f[i] = v;
    }
    if (i < NCHUNK * 2 * 16 * 8) {          // 32768
        int j  = i & 7;
        int ci = (i >> 3) & 15;
        int c  = (i >> 7) & 1;
        int cc = i >> 8;
        int g = ci >> 3, e = ci & 7;
        int k = 8 * g + j;
        int fl = (k & 3) + 8 * ((k >> 2) & 1) + 4 * (k >> 3);
        int f = 32 * cc + 16 * c + fl;
        w2f[i] = (_Float16)w2[e * FFN_DIM + f];
    }
}

// ---------------------------------------------------------------------------
// Main kernel, weights-stationary: block = (class p, token-group tg).
// Stage class-p tables (48KB) into LDS ONCE; 8 waves each own one 32-token
// tile and loop 32 chunks purely from LDS (no L2 hotspot in the hot loop).
// Partial results (f-split) written to ws; reduce kernel sums 4 classes + b2.
// ---------------------------------------------------------------------------
__global__ __launch_bounds__(512, 4) void ffq_mfma_kernel(
    const float* __restrict__ x,
    const float* __restrict__ theta,
    const _Float16* __restrict__ w1f,   // [128][64][8]
    const _Float16* __restrict__ w2f,   // [128][2][16][8]
    float* __restrict__ partial,        // [CLS][n_tok][8]
    int n_tok)
{
    __shared__ _Float16 w1s[CCHUNK][64][8];     // 32KB
    __shared__ _Float16 w2s[CCHUNK][2][16][8];  // 16KB

    const int tid  = threadIdx.x;
    const int lane = tid & 63;
    const int wave = tid >> 6;          // 0..7
    const int l31  = lane & 31;
    const int g    = lane >> 5;

    const int cls = blockIdx.x & (CLS - 1);
    const int tg  = blockIdx.x >> 2;
    const int c0  = cls * CCHUNK;

    // ---- stage this class's tables into LDS (uint4 = 8 halves per thread) --
    {
        const uint4* s1 = (const uint4*)(w1f + (size_t)c0 * 512);
        uint4* d1p = (uint4*)&w1s[0][0][0];
        #pragma unroll
        for (int i = 0; i < (CCHUNK * 512 / 8) / TPB; ++i)     // 4 iters
            d1p[tid + i * TPB] = s1[tid + i * TPB];
        const uint4* s2 = (const uint4*)(w2f + (size_t)c0 * 256);
        uint4* d2p = (uint4*)&w2s[0][0][0][0];
        #pragma unroll
        for (int i = 0; i < (CCHUNK * 256 / 8) / TPB; ++i)     // 2 iters
            d2p[tid + i * TPB] = s2[tid + i * TPB];
    }

    // ---- B1 operand: q^T fragment (col = token = lane&31) ----
    const float cth = cosf(theta[0]);
    const int tok = tg * TOKB + wave * 32 + l31;
    f16x8 bq = {};
    if (g == 0) {
        int rt = tok < n_tok ? tok : (n_tok - 1);
        const f32x4* xp = (const f32x4*)(x + (size_t)rt * 8);
        f32x4 x0 = xp[0], x1 = xp[1];
        bq[0] = (_Float16)(cth * cosf(x0.x));
        bq[1] = (_Float16)(cth * cosf(x0.y));
        bq[2] = (_Float16)(cth * cosf(x0.z));
        bq[3] = (_Float16)(cth * cosf(x0.w));
        bq[4] = (_Float16)(cth * cosf(x1.x));
        bq[5] = (_Float16)(cth * cosf(x1.y));
        bq[6] = (_Float16)(cth * cosf(x1.z));
        bq[7] = (_Float16)(cth * cosf(x1.w));
    } else {
        bq[0] = (_Float16)1.0f;   // k=8 column: multiplies the b1 row of W1frag
    }

    __syncthreads();

    f32x16 acc = {};
    const f32x16 zero16 = {};
    // A-operand row for G2: all lanes load entry (g, l31&7); rows 8..31 are
    // duplicates ignored in the epilogue. Same-address LDS reads broadcast.
    const int ci = g * 8 + (l31 & 7);
    const _Float16* a1p = &w1s[0][lane][0];        // + lc*512
    const _Float16* a2p = &w2s[0][0][ci][0];       // + lc*256 (+128 half c=1)

    union U8 { f16x8 v; h16x2 p[4]; };
    const h16x2 hz = {(__fp16)0.0f, (__fp16)0.0f};

    #pragma unroll 2
    for (int lc = 0; lc < CCHUNK; ++lc) {
        f16x8 A1  = *(const f16x8*)(a1p + lc * 512);
        f16x8 A2a = *(const f16x8*)(a2p + lc * 256);
        f16x8 A2b = *(const f16x8*)(a2p + lc * 256 + 128);

        // GEMM1: h-tile (32 f x 32 tok), bias folded in via k=8
        f32x16 d1 = __builtin_amdgcn_mfma_f32_32x32x16_f16(A1, bq, zero16, 0, 0, 0);

        // pack to fp16 + relu via v_pk_max_f16
        U8 ua, ub;
        #pragma unroll
        for (int v = 0; v < 4; ++v) {
            ua.p[v] = __builtin_amdgcn_cvt_pkrtz(d1[2 * v],     d1[2 * v + 1]);
            ub.p[v] = __builtin_amdgcn_cvt_pkrtz(d1[8 + 2 * v], d1[8 + 2 * v + 1]);
        }
        #pragma unroll
        for (int v = 0; v < 4; ++v) {
            ua.p[v] = __builtin_elementwise_max(ua.p[v], hz);
            ub.p[v] = __builtin_elementwise_max(ub.p[v], hz);
        }

        // GEMM2: two K=16 halves of the 32-f chunk
        acc = __builtin_amdgcn_mfma_f32_32x32x16_f16(A2a, ua.v, acc, 0, 0, 0);
        acc = __builtin_amdgcn_mfma_f32_32x32x16_f16(A2b, ub.v, acc, 0, 0, 0);
    }

    // lane holds out rows e = 4g + r (r=0..3) for token col = l31
    if (tok < n_tok) {
        f32x4 o = {acc[0], acc[1], acc[2], acc[3]};
        *(f32x4*)(partial + ((size_t)cls * n_tok + tok) * 8 + 4 * g) = o;
    }
}

// ---------------------------------------------------------------------------
// Reduce: out = sum over 4 classes + b2. One float4 per thread.
// ---------------------------------------------------------------------------
__global__ __launch_bounds__(256) void ffq_reduce_kernel(
    const float* __restrict__ partial, const float* __restrict__ b2,
    float* __restrict__ out, int n_tok)
{
    int j = blockIdx.x * 256 + threadIdx.x;    // float4 index
    int nq = n_tok * 2;
    if (j < nq) {
        const f32x4* p = (const f32x4*)partial;
        size_t stride = (size_t)n_tok * 2;
        f32x4 s = p[j];
        s = s + p[j + stride];
        s = s + p[j + 2 * stride];
        s = s + p[j + 3 * stride];
        f32x4 bb = ((const f32x4*)b2)[j & 1];
        ((f32x4*)out)[j] = s + bb;
    }
}

// ---------------------------------------------------------------------------
// Fallback (ws too small): round-1 fp32 VALU kernel, direct w2 reads.
// ---------------------------------------------------------------------------
__global__ __launch_bounds__(256, 4) void ffq_valu_kernel(
    const float* __restrict__ x, const float* __restrict__ theta,
    const float* __restrict__ w1, const float* __restrict__ b1,
    const float* __restrict__ w2, const float* __restrict__ b2,
    float* __restrict__ out, int n_tok)
{
    __shared__ float part[4][64][9];
    const int tid = threadIdx.x;
    const int lane = tid & 63;
    const int wave = __builtin_amdgcn_readfirstlane(tid >> 6);
    const int tok = blockIdx.x * 64 + lane;
    const int rtok = tok < n_tok ? tok : n_tok - 1;
    const float cth = cosf(theta[0]);
    const f32x4* xv = (const f32x4*)(x + (size_t)rtok * 8);
    f32x4 x0 = xv[0], x1 = xv[1];
    float q[8];
    q[0]=cth*cosf(x0.x); q[1]=cth*cosf(x0.y); q[2]=cth*cosf(x0.z); q[3]=cth*cosf(x0.w);
    q[4]=cth*cosf(x1.x); q[5]=cth*cosf(x1.y); q[6]=cth*cosf(x1.z); q[7]=cth*cosf(x1.w);
    float acc[8];
    #pragma unroll
    for (int e = 0; e < 8; ++e) acc[e] = 0.0f;
    const int f0 = wave * (FFN_DIM / 4), f1 = f0 + (FFN_DIM / 4);
    #pragma unroll 2
    for (int f = f0; f < f1; ++f) {
        const f32x4* w1r = (const f32x4*)(w1 + (size_t)f * 8);
        f32x4 u0 = w1r[0], u1 = w1r[1];
        float h = b1[f];
        h = fmaf(u0.x,q[0],h); h = fmaf(u0.y,q[1],h); h = fmaf(u0.z,q[2],h); h = fmaf(u0.w,q[3],h);
        h = fmaf(u1.x,q[4],h); h = fmaf(u1.y,q[5],h); h = fmaf(u1.z,q[6],h); h = fmaf(u1.w,q[7],h);
        h = fmaxf(h, 0.0f);
        #pragma unroll
        for (int e = 0; e < 8; ++e) acc[e] = fmaf(h, w2[e * FFN_DIM + f], acc[e]);
    }
    #pragma unroll
    for (int e = 0; e < 8; ++e) part[wave][lane][e] = acc[e];
    __syncthreads();
    for (int i = tid; i < 64 * 8; i += 256) {
        int t = i >> 3, e = i & 7;
        int gt = blockIdx.x * 64 + t;
        if (gt < n_tok)
            out[(size_t)gt * 8 + e] = part[0][t][e] + part[1][t][e]
                                    + part[2][t][e] + part[3][t][e] + b2[e];
    }
}

extern "C" void kernel_launch(void* const* d_in, const int* in_sizes, int n_in,
                              void* d_out, int out_size, void* d_ws, size_t ws_size,
                              hipStream_t stream) {
    const float* x     = (const float*)d_in[0];
    const float* theta = (const float*)d_in[1];
    const float* w1    = (const float*)d_in[2];
    const float* b1    = (const float*)d_in[3];
    const float* w2    = (const float*)d_in[4];
    const float* b2    = (const float*)d_in[5];
    float* out = (float*)d_out;
    const int n_tok = out_size / 8;

    const size_t W1F_BYTES = (size_t)NCHUNK * 64 * 8 * sizeof(_Float16);   // 128KB
    const size_t W2F_BYTES = (size_t)NCHUNK * 2 * 16 * 8 * sizeof(_Float16); // 64KB
    const size_t PART_BYTES = (size_t)CLS * n_tok * 8 * sizeof(float);     // 8MB

    if (ws_size >= W1F_BYTES + W2F_BYTES + PART_BYTES) {
        _Float16* w1f = (_Float16*)d_ws;
        _Float16* w2f = (_Float16*)((char*)d_ws + W1F_BYTES);
        float* partial = (float*)((char*)d_ws + W1F_BYTES + W2F_BYTES);
        build_frags_kernel<<<(NCHUNK * 64 * 8 + 255) / 256, 256, 0, stream>>>(
            w1, b1, w2, w1f, w2f);
        int n_tg = (n_tok + TOKB - 1) / TOKB;          // 256 for 65536 tokens
        ffq_mfma_kernel<<<CLS * n_tg, TPB, 0, stream>>>(x, theta, w1f, w2f,
                                                        partial, n_tok);
        int nq = n_tok * 2;                            // float4s in out
        ffq_reduce_kernel<<<(nq + 255) / 256, 256, 0, stream>>>(partial, b2,
                                                                out, n_tok);
    } else {
        int grid = (n_tok + 63) / 64;
        ffq_valu_kernel<<<grid, 256, 0, stream>>>(x, theta, w1, b1, w2, b2, out,
                                                  n_tok);
    }
}

// Round 15
// 33.566 us; speedup vs baseline: 1.1150x; 1.1150x over previous
//
#include <hip/hip_runtime.h>
#include <math.h>

#define FFN_DIM 4096
#define NCHUNK  128        // 4096 / 32

typedef _Float16 f16x8 __attribute__((ext_vector_type(8)));
typedef __fp16   h16x2 __attribute__((ext_vector_type(2)));
typedef float    f32x16 __attribute__((ext_vector_type(16)));
typedef float    f32x4  __attribute__((ext_vector_type(4)));

// ---------------------------------------------------------------------------
// Pre-kernel: build fp16 MFMA fragment tables in workspace.
//  w1f  [128][64][8] f16 (128KB): lanes 0-31 = W1 rows (k=0..7); lanes 32-63 =
//        {b1, 0,...} so the constant-1 column of q^T adds the bias (k=8).
//  w2f  [128][2][16][8] f16 (64KB): W2 rows permuted so GEMM1's C/D register
//        order feeds GEMM2's B operand directly (verified: absmax 3.9e-3).
// ---------------------------------------------------------------------------
__global__ void build_frags_kernel(const float* __restrict__ w1,
                                   const float* __restrict__ b1,
                                   const float* __restrict__ w2,
                                   _Float16* __restrict__ w1f,
                                   _Float16* __restrict__ w2f) {
    int i = blockIdx.x * 256 + threadIdx.x;
    if (i < NCHUNK * 64 * 8) {              // 65536
        int j    = i & 7;
        int lane = (i >> 3) & 63;
        int cc   = i >> 9;
        _Float16 v;
        if (lane < 32) v = (_Float16)w1[(cc * 32 + lane) * 8 + j];
        else           v = (j == 0) ? (_Float16)b1[cc * 32 + (lane & 31)]
                                    : (_Float16)0.0f;
        w1f[i] = v;
    }
    if (i < NCHUNK * 2 * 16 * 8) {          // 32768
        int j  = i & 7;
        int ci = (i >> 3) & 15;
        int c  = (i >> 7) & 1;
        int cc = i >> 8;
        int g = ci >> 3, e = ci & 7;
        int k = 8 * g + j;
        int fl = (k & 3) + 8 * ((k >> 2) & 1) + 4 * (k >> 3);
        int f = 32 * cc + 16 * c + fl;
        w2f[i] = (_Float16)w2[e * FFN_DIM + f];
    }
}

// ---------------------------------------------------------------------------
// Main kernel: block = 4 waves = 128 tokens (4 tiles). Wave w owns chunks
// [32w,32w+32) (f-split) for ALL FOUR tiles -> 12 MFMA/chunk/wave across 4
// independent dependency chains (pipe self-saturation at 2 waves/SIMD).
// Weight frags loaded once per chunk feed 4 tiles. LDS reduce at the end.
// ---------------------------------------------------------------------------
__global__ __launch_bounds__(256, 2) void ffq_mfma_kernel(
    const float* __restrict__ x,
    const float* __restrict__ theta,
    const _Float16* __restrict__ w1f,   // [128][64][8]
    const _Float16* __restrict__ w2f,   // [128][2][16][8]
    const float* __restrict__ b2,
    float* __restrict__ out,
    int n_tok)
{
    __shared__ float part[4][4][64][4];    // 16KB

    const int tid  = threadIdx.x;
    const int lane = tid & 63;
    const int wave = tid >> 6;
    const int l31  = lane & 31;
    const int g    = lane >> 5;

    const int tb = blockIdx.x * 128;
    const float cth = cosf(theta[0]);

    // ---- B1 operands: q^T fragments for the four tiles (col = tok = lane&31)
    f16x8 bq0 = {}, bq1 = {}, bq2 = {}, bq3 = {};
    if (g == 0) {
#define LOAD_BQ(BQ, TOFF)                                                  \
        {                                                                  \
            int t_ = tb + (TOFF) + l31;                                    \
            int r_ = t_ < n_tok ? t_ : (n_tok - 1);                        \
            const f32x4* xp_ = (const f32x4*)(x + (size_t)r_ * 8);         \
            f32x4 u_ = xp_[0], v_ = xp_[1];                                \
            BQ[0] = (_Float16)(cth * cosf(u_.x));                          \
            BQ[1] = (_Float16)(cth * cosf(u_.y));                          \
            BQ[2] = (_Float16)(cth * cosf(u_.z));                          \
            BQ[3] = (_Float16)(cth * cosf(u_.w));                          \
            BQ[4] = (_Float16)(cth * cosf(v_.x));                          \
            BQ[5] = (_Float16)(cth * cosf(v_.y));                          \
            BQ[6] = (_Float16)(cth * cosf(v_.z));                          \
            BQ[7] = (_Float16)(cth * cosf(v_.w));                          \
        }
        LOAD_BQ(bq0, 0)
        LOAD_BQ(bq1, 32)
        LOAD_BQ(bq2, 64)
        LOAD_BQ(bq3, 96)
#undef LOAD_BQ
    } else {
        bq0[0] = (_Float16)1.0f;   // k=8 column: multiplies the b1 row of W1frag
        bq1[0] = (_Float16)1.0f;
        bq2[0] = (_Float16)1.0f;
        bq3[0] = (_Float16)1.0f;
    }

    f32x16 acc0 = {}, acc1 = {}, acc2 = {}, acc3 = {};
    const f32x16 zero16 = {};

    // A-operand row for G2: all lanes load entry (g, l31&7); rows 8..31 are
    // duplicates whose outputs are never read.
    const int ci = g * 8 + (l31 & 7);
    const _Float16* a1p = w1f + (size_t)lane * 8;   // + cc*512
    const _Float16* a2p = w2f + (size_t)ci * 8;     // + cc*256 (+128 half c=1)

    union U8 { f16x8 v; h16x2 p[4]; };
    const h16x2 hz = {(__fp16)0.0f, (__fp16)0.0f};

    const int c0 = wave * (NCHUNK / 4);
    const int c1 = c0 + (NCHUNK / 4);

    for (int cc = c0; cc < c1; ++cc) {
        f16x8 A1  = *(const f16x8*)(a1p + (size_t)cc * 512);
        f16x8 A2a = *(const f16x8*)(a2p + (size_t)cc * 256);
        f16x8 A2b = *(const f16x8*)(a2p + (size_t)cc * 256 + 128);

        // ---- pair 0: tiles 0,1 ----
        f32x16 dA = __builtin_amdgcn_mfma_f32_32x32x16_f16(A1, bq0, zero16, 0, 0, 0);
        f32x16 dB = __builtin_amdgcn_mfma_f32_32x32x16_f16(A1, bq1, zero16, 0, 0, 0);
        U8 uaA, ubA, uaB, ubB;
        #pragma unroll
        for (int v = 0; v < 4; ++v) {
            uaA.p[v] = __builtin_amdgcn_cvt_pkrtz(dA[2 * v],     dA[2 * v + 1]);
            ubA.p[v] = __builtin_amdgcn_cvt_pkrtz(dA[8 + 2 * v], dA[8 + 2 * v + 1]);
            uaB.p[v] = __builtin_amdgcn_cvt_pkrtz(dB[2 * v],     dB[2 * v + 1]);
            ubB.p[v] = __builtin_amdgcn_cvt_pkrtz(dB[8 + 2 * v], dB[8 + 2 * v + 1]);
        }
        #pragma unroll
        for (int v = 0; v < 4; ++v) {
            uaA.p[v] = __builtin_elementwise_max(uaA.p[v], hz);
            ubA.p[v] = __builtin_elementwise_max(ubA.p[v], hz);
            uaB.p[v] = __builtin_elementwise_max(uaB.p[v], hz);
            ubB.p[v] = __builtin_elementwise_max(ubB.p[v], hz);
        }
        acc0 = __builtin_amdgcn_mfma_f32_32x32x16_f16(A2a, uaA.v, acc0, 0, 0, 0);
        acc0 = __builtin_amdgcn_mfma_f32_32x32x16_f16(A2b, ubA.v, acc0, 0, 0, 0);
        acc1 = __builtin_amdgcn_mfma_f32_32x32x16_f16(A2a, uaB.v, acc1, 0, 0, 0);
        acc1 = __builtin_amdgcn_mfma_f32_32x32x16_f16(A2b, ubB.v, acc1, 0, 0, 0);

        // ---- pair 1: tiles 2,3 ----
        f32x16 dC = __builtin_amdgcn_mfma_f32_32x32x16_f16(A1, bq2, zero16, 0, 0, 0);
        f32x16 dD = __builtin_amdgcn_mfma_f32_32x32x16_f16(A1, bq3, zero16, 0, 0, 0);
        U8 uaC, ubC, uaD, ubD;
        #pragma unroll
        for (int v = 0; v < 4; ++v) {
            uaC.p[v] = __builtin_amdgcn_cvt_pkrtz(dC[2 * v],     dC[2 * v + 1]);
            ubC.p[v] = __builtin_amdgcn_cvt_pkrtz(dC[8 + 2 * v], dC[8 + 2 * v + 1]);
            uaD.p[v] = __builtin_amdgcn_cvt_pkrtz(dD[2 * v],     dD[2 * v + 1]);
            ubD.p[v] = __builtin_amdgcn_cvt_pkrtz(dD[8 + 2 * v], dD[8 + 2 * v + 1]);
        }
        #pragma unroll
        for (int v = 0; v < 4; ++v) {
            uaC.p[v] = __builtin_elementwise_max(uaC.p[v], hz);
            ubC.p[v] = __builtin_elementwise_max(ubC.p[v], hz);
            uaD.p[v] = __builtin_elementwise_max(uaD.p[v], hz);
            ubD.p[v] = __builtin_elementwise_max(ubD.p[v], hz);
        }
        acc2 = __builtin_amdgcn_mfma_f32_32x32x16_f16(A2a, uaC.v, acc2, 0, 0, 0);
        acc2 = __builtin_amdgcn_mfma_f32_32x32x16_f16(A2b, ubC.v, acc2, 0, 0, 0);
        acc3 = __builtin_amdgcn_mfma_f32_32x32x16_f16(A2a, uaD.v, acc3, 0, 0, 0);
        acc3 = __builtin_amdgcn_mfma_f32_32x32x16_f16(A2b, ubD.v, acc3, 0, 0, 0);
    }

    // rows e = 4g + r live in acc*[0..3]
    #pragma unroll
    for (int r = 0; r < 4; ++r) {
        part[wave][0][lane][r] = acc0[r];
        part[wave][1][lane][r] = acc1[r];
        part[wave][2][lane][r] = acc2[r];
        part[wave][3][lane][r] = acc3[r];
    }
    __syncthreads();

    // 1024 outputs per block (128 tok x 8 e), 4 per thread
    for (int i = tid; i < 128 * 8; i += 256) {
        int t = i >> 3, e = i & 7;
        int gt = tb + t;
        if (gt < n_tok) {
            int tt = t >> 5;                // which tile
            int tl = t & 31;
            int sl = (e >> 2) * 32 + tl;    // source lane for this (tok, e)
            int r  = e & 3;
            float s = part[0][tt][sl][r] + part[1][tt][sl][r]
                    + part[2][tt][sl][r] + part[3][tt][sl][r] + b2[e];
            out[(size_t)gt * 8 + e] = s;
        }
    }
}

// ---------------------------------------------------------------------------
// Fallback (ws too small): round-1 fp32 VALU kernel, direct w2 reads.
// ---------------------------------------------------------------------------
__global__ __launch_bounds__(256, 4) void ffq_valu_kernel(
    const float* __restrict__ x, const float* __restrict__ theta,
    const float* __restrict__ w1, const float* __restrict__ b1,
    const float* __restrict__ w2, const float* __restrict__ b2,
    float* __restrict__ out, int n_tok)
{
    __shared__ float part[4][64][9];
    const int tid = threadIdx.x;
    const int lane = tid & 63;
    const int wave = __builtin_amdgcn_readfirstlane(tid >> 6);
    const int tok = blockIdx.x * 64 + lane;
    const int rtok = tok < n_tok ? tok : n_tok - 1;
    const float cth = cosf(theta[0]);
    const f32x4* xv = (const f32x4*)(x + (size_t)rtok * 8);
    f32x4 x0 = xv[0], x1 = xv[1];
    float q[8];
    q[0]=cth*cosf(x0.x); q[1]=cth*cosf(x0.y); q[2]=cth*cosf(x0.z); q[3]=cth*cosf(x0.w);
    q[4]=cth*cosf(x1.x); q[5]=cth*cosf(x1.y); q[6]=cth*cosf(x1.z); q[7]=cth*cosf(x1.w);
    float acc[8];
    #pragma unroll
    for (int e = 0; e < 8; ++e) acc[e] = 0.0f;
    const int f0 = wave * (FFN_DIM / 4), f1 = f0 + (FFN_DIM / 4);
    #pragma unroll 2
    for (int f = f0; f < f1; ++f) {
        const f32x4* w1r = (const f32x4*)(w1 + (size_t)f * 8);
        f32x4 u0 = w1r[0], u1 = w1r[1];
        float h = b1[f];
        h = fmaf(u0.x,q[0],h); h = fmaf(u0.y,q[1],h); h = fmaf(u0.z,q[2],h); h = fmaf(u0.w,q[3],h);
        h = fmaf(u1.x,q[4],h); h = fmaf(u1.y,q[5],h); h = fmaf(u1.z,q[6],h); h = fmaf(u1.w,q[7],h);
        h = fmaxf(h, 0.0f);
        #pragma unroll
        for (int e = 0; e < 8; ++e) acc[e] = fmaf(h, w2[e * FFN_DIM + f], acc[e]);
    }
    #pragma unroll
    for (int e = 0; e < 8; ++e) part[wave][lane][e] = acc[e];
    __syncthreads();
    for (int i = tid; i < 64 * 8; i += 256) {
        int t = i >> 3, e = i & 7;
        int gt = blockIdx.x * 64 + t;
        if (gt < n_tok)
            out[(size_t)gt * 8 + e] = part[0][t][e] + part[1][t][e]
                                    + part[2][t][e] + part[3][t][e] + b2[e];
    }
}

extern "C" void kernel_launch(void* const* d_in, const int* in_sizes, int n_in,
                              void* d_out, int out_size, void* d_ws, size_t ws_size,
                              hipStream_t stream) {
    const float* x     = (const float*)d_in[0];
    const float* theta = (const float*)d_in[1];
    const float* w1    = (const float*)d_in[2];
    const float* b1    = (const float*)d_in[3];
    const float* w2    = (const float*)d_in[4];
    const float* b2    = (const float*)d_in[5];
    float* out = (float*)d_out;
    const int n_tok = out_size / 8;

    const size_t W1F_BYTES = (size_t)NCHUNK * 64 * 8 * sizeof(_Float16);   // 128KB
    const size_t W2F_BYTES = (size_t)NCHUNK * 2 * 16 * 8 * sizeof(_Float16); // 64KB

    if (ws_size >= W1F_BYTES + W2F_BYTES) {
        _Float16* w1f = (_Float16*)d_ws;
        _Float16* w2f = (_Float16*)((char*)d_ws + W1F_BYTES);
        build_frags_kernel<<<(NCHUNK * 64 * 8 + 255) / 256, 256, 0, stream>>>(
            w1, b1, w2, w1f, w2f);
        int blocks = (n_tok + 127) / 128;   // four 32-token tiles per block
        ffq_mfma_kernel<<<blocks, 256, 0, stream>>>(x, theta, w1f, w2f, b2, out,
                                                    n_tok);
    } else {
        int grid = (n_tok + 63) / 64;
        ffq_valu_kernel<<<grid, 256, 0, stream>>>(x, theta, w1, b1, w2, b2, out,
                                                  n_tok);
    }
}

// Round 16
// 33.088 us; speedup vs baseline: 1.1311x; 1.0144x over previous
//
#include <hip/hip_runtime.h>
#include <math.h>

#define FFN_DIM 4096
#define NCHUNK  128        // 4096 / 32

typedef _Float16 f16x8 __attribute__((ext_vector_type(8)));
typedef __fp16   h16x2 __attribute__((ext_vector_type(2)));
typedef float    f32x16 __attribute__((ext_vector_type(16)));
typedef float    f32x4  __attribute__((ext_vector_type(4)));

// ---------------------------------------------------------------------------
// Pre-kernel: build fp16 MFMA fragment tables in workspace.
//  w1f  [128][64][8] f16 (128KB): lanes 0-31 = W1 rows (k=0..7); lanes 32-63 =
//        {b1, 0,...} so the constant-1 column of q^T adds the bias (k=8).
//  w2f  [128][2][16][8] f16 (64KB): W2 rows permuted so GEMM1's C/D register
//        order feeds GEMM2's B operand directly (verified: absmax 3.9e-3).
// ---------------------------------------------------------------------------
__global__ void build_frags_kernel(const float* __restrict__ w1,
                                   const float* __restrict__ b1,
                                   const float* __restrict__ w2,
                                   _Float16* __restrict__ w1f,
                                   _Float16* __restrict__ w2f) {
    int i = blockIdx.x * 256 + threadIdx.x;
    if (i < NCHUNK * 64 * 8) {              // 65536
        int j    = i & 7;
        int lane = (i >> 3) & 63;
        int cc   = i >> 9;
        _Float16 v;
        if (lane < 32) v = (_Float16)w1[(cc * 32 + lane) * 8 + j];
        else           v = (j == 0) ? (_Float16)b1[cc * 32 + (lane & 31)]
                                    : (_Float16)0.0f;
        w1f[i] = v;
    }
    if (i < NCHUNK * 2 * 16 * 8) {          // 32768
        int j  = i & 7;
        int ci = (i >> 3) & 15;
        int c  = (i >> 7) & 1;
        int cc = i >> 8;
        int g = ci >> 3, e = ci & 7;
        int k = 8 * g + j;
        int fl = (k & 3) + 8 * ((k >> 2) & 1) + 4 * (k >> 3);
        int f = 32 * cc + 16 * c + fl;
        w2f[i] = (_Float16)w2[e * FFN_DIM + f];
    }
}

// ---------------------------------------------------------------------------
// Main kernel: block = 4 waves = 128 tokens (4 tiles/wave, f-split by wave).
// Software-pipelined chunk loop: frags prefetched one iteration ahead;
// all 4 G1s issued back-to-back; G2s interleaved round-robin across the 4
// accumulators so same-acc dependent MFMAs sit ~4 MFMA apart.
// ---------------------------------------------------------------------------
__global__ __launch_bounds__(256, 2) void ffq_mfma_kernel(
    const float* __restrict__ x,
    const float* __restrict__ theta,
    const _Float16* __restrict__ w1f,   // [128][64][8]
    const _Float16* __restrict__ w2f,   // [128][2][16][8]
    const float* __restrict__ b2,
    float* __restrict__ out,
    int n_tok)
{
    __shared__ float part[4][4][64][4];    // 16KB

    const int tid  = threadIdx.x;
    const int lane = tid & 63;
    const int wave = tid >> 6;
    const int l31  = lane & 31;
    const int g    = lane >> 5;

    const int tb = blockIdx.x * 128;
    const float cth = cosf(theta[0]);

    // ---- B1 operands: q^T fragments for the four tiles (col = tok = lane&31)
    f16x8 bq0 = {}, bq1 = {}, bq2 = {}, bq3 = {};
    if (g == 0) {
#define LOAD_BQ(BQ, TOFF)                                                  \
        {                                                                  \
            int t_ = tb + (TOFF) + l31;                                    \
            int r_ = t_ < n_tok ? t_ : (n_tok - 1);                        \
            const f32x4* xp_ = (const f32x4*)(x + (size_t)r_ * 8);         \
            f32x4 u_ = xp_[0], v_ = xp_[1];                                \
            BQ[0] = (_Float16)(cth * cosf(u_.x));                          \
            BQ[1] = (_Float16)(cth * cosf(u_.y));                          \
            BQ[2] = (_Float16)(cth * cosf(u_.z));                          \
            BQ[3] = (_Float16)(cth * cosf(u_.w));                          \
            BQ[4] = (_Float16)(cth * cosf(v_.x));                          \
            BQ[5] = (_Float16)(cth * cosf(v_.y));                          \
            BQ[6] = (_Float16)(cth * cosf(v_.z));                          \
            BQ[7] = (_Float16)(cth * cosf(v_.w));                          \
        }
        LOAD_BQ(bq0, 0)
        LOAD_BQ(bq1, 32)
        LOAD_BQ(bq2, 64)
        LOAD_BQ(bq3, 96)
#undef LOAD_BQ
    } else {
        bq0[0] = (_Float16)1.0f;   // k=8 column: multiplies the b1 row of W1frag
        bq1[0] = (_Float16)1.0f;
        bq2[0] = (_Float16)1.0f;
        bq3[0] = (_Float16)1.0f;
    }

    f32x16 acc0 = {}, acc1 = {}, acc2 = {}, acc3 = {};
    const f32x16 zero16 = {};

    // A-operand row for G2: all lanes load entry (g, l31&7); rows 8..31 are
    // duplicates whose outputs are never read.
    const int ci = g * 8 + (l31 & 7);
    const _Float16* a1p = w1f + (size_t)lane * 8;   // + cc*512
    const _Float16* a2p = w2f + (size_t)ci * 8;     // + cc*256 (+128 half c=1)

    union U8 { f16x8 v; h16x2 p[4]; };
    const h16x2 hz = {(__fp16)0.0f, (__fp16)0.0f};

    const int c0 = wave * (NCHUNK / 4);
    const int c1 = c0 + (NCHUNK / 4);

    // prologue: load chunk c0's fragments
    f16x8 A1  = *(const f16x8*)(a1p + (size_t)c0 * 512);
    f16x8 A2a = *(const f16x8*)(a2p + (size_t)c0 * 256);
    f16x8 A2b = *(const f16x8*)(a2p + (size_t)c0 * 256 + 128);

    for (int cc = c0; cc < c1; ++cc) {
        // ---- prefetch next chunk's fragments (used next iteration) ----
        f16x8 nA1 = A1, nA2a = A2a, nA2b = A2b;
        if (cc + 1 < c1) {
            nA1  = *(const f16x8*)(a1p + (size_t)(cc + 1) * 512);
            nA2a = *(const f16x8*)(a2p + (size_t)(cc + 1) * 256);
            nA2b = *(const f16x8*)(a2p + (size_t)(cc + 1) * 256 + 128);
        }

        // ---- all four G1s back-to-back (independent) ----
        f32x16 dA = __builtin_amdgcn_mfma_f32_32x32x16_f16(A1, bq0, zero16, 0, 0, 0);
        f32x16 dB = __builtin_amdgcn_mfma_f32_32x32x16_f16(A1, bq1, zero16, 0, 0, 0);
        f32x16 dC = __builtin_amdgcn_mfma_f32_32x32x16_f16(A1, bq2, zero16, 0, 0, 0);
        f32x16 dD = __builtin_amdgcn_mfma_f32_32x32x16_f16(A1, bq3, zero16, 0, 0, 0);

        // ---- pack + relu for all four tiles ----
        U8 uaA, ubA, uaB, ubB, uaC, ubC, uaD, ubD;
        #pragma unroll
        for (int v = 0; v < 4; ++v) {
            uaA.p[v] = __builtin_amdgcn_cvt_pkrtz(dA[2 * v],     dA[2 * v + 1]);
            ubA.p[v] = __builtin_amdgcn_cvt_pkrtz(dA[8 + 2 * v], dA[8 + 2 * v + 1]);
            uaB.p[v] = __builtin_amdgcn_cvt_pkrtz(dB[2 * v],     dB[2 * v + 1]);
            ubB.p[v] = __builtin_amdgcn_cvt_pkrtz(dB[8 + 2 * v], dB[8 + 2 * v + 1]);
            uaC.p[v] = __builtin_amdgcn_cvt_pkrtz(dC[2 * v],     dC[2 * v + 1]);
            ubC.p[v] = __builtin_amdgcn_cvt_pkrtz(dC[8 + 2 * v], dC[8 + 2 * v + 1]);
            uaD.p[v] = __builtin_amdgcn_cvt_pkrtz(dD[2 * v],     dD[2 * v + 1]);
            ubD.p[v] = __builtin_amdgcn_cvt_pkrtz(dD[8 + 2 * v], dD[8 + 2 * v + 1]);
        }
        #pragma unroll
        for (int v = 0; v < 4; ++v) {
            uaA.p[v] = __builtin_elementwise_max(uaA.p[v], hz);
            ubA.p[v] = __builtin_elementwise_max(ubA.p[v], hz);
            uaB.p[v] = __builtin_elementwise_max(uaB.p[v], hz);
            ubB.p[v] = __builtin_elementwise_max(ubB.p[v], hz);
            uaC.p[v] = __builtin_elementwise_max(uaC.p[v], hz);
            ubC.p[v] = __builtin_elementwise_max(ubC.p[v], hz);
            uaD.p[v] = __builtin_elementwise_max(uaD.p[v], hz);
            ubD.p[v] = __builtin_elementwise_max(ubD.p[v], hz);
        }

        // ---- G2s round-robin across accumulators (dep distance = 4 MFMA) ----
        acc0 = __builtin_amdgcn_mfma_f32_32x32x16_f16(A2a, uaA.v, acc0, 0, 0, 0);
        acc1 = __builtin_amdgcn_mfma_f32_32x32x16_f16(A2a, uaB.v, acc1, 0, 0, 0);
        acc2 = __builtin_amdgcn_mfma_f32_32x32x16_f16(A2a, uaC.v, acc2, 0, 0, 0);
        acc3 = __builtin_amdgcn_mfma_f32_32x32x16_f16(A2a, uaD.v, acc3, 0, 0, 0);
        acc0 = __builtin_amdgcn_mfma_f32_32x32x16_f16(A2b, ubA.v, acc0, 0, 0, 0);
        acc1 = __builtin_amdgcn_mfma_f32_32x32x16_f16(A2b, ubB.v, acc1, 0, 0, 0);
        acc2 = __builtin_amdgcn_mfma_f32_32x32x16_f16(A2b, ubC.v, acc2, 0, 0, 0);
        acc3 = __builtin_amdgcn_mfma_f32_32x32x16_f16(A2b, ubD.v, acc3, 0, 0, 0);

        A1 = nA1; A2a = nA2a; A2b = nA2b;
    }

    // rows e = 4g + r live in acc*[0..3]
    #pragma unroll
    for (int r = 0; r < 4; ++r) {
        part[wave][0][lane][r] = acc0[r];
        part[wave][1][lane][r] = acc1[r];
        part[wave][2][lane][r] = acc2[r];
        part[wave][3][lane][r] = acc3[r];
    }
    __syncthreads();

    // 1024 outputs per block (128 tok x 8 e), 4 per thread
    for (int i = tid; i < 128 * 8; i += 256) {
        int t = i >> 3, e = i & 7;
        int gt = tb + t;
        if (gt < n_tok) {
            int tt = t >> 5;                // which tile
            int tl = t & 31;
            int sl = (e >> 2) * 32 + tl;    // source lane for this (tok, e)
            int r  = e & 3;
            float s = part[0][tt][sl][r] + part[1][tt][sl][r]
                    + part[2][tt][sl][r] + part[3][tt][sl][r] + b2[e];
            out[(size_t)gt * 8 + e] = s;
        }
    }
}

// ---------------------------------------------------------------------------
// Fallback (ws too small): round-1 fp32 VALU kernel, direct w2 reads.
// ---------------------------------------------------------------------------
__global__ __launch_bounds__(256, 4) void ffq_valu_kernel(
    const float* __restrict__ x, const float* __restrict__ theta,
    const float* __restrict__ w1, const float* __restrict__ b1,
    const float* __restrict__ w2, const float* __restrict__ b2,
    float* __restrict__ out, int n_tok)
{
    __shared__ float part[4][64][9];
    const int tid = threadIdx.x;
    const int lane = tid & 63;
    const int wave = __builtin_amdgcn_readfirstlane(tid >> 6);
    const int tok = blockIdx.x * 64 + lane;
    const int rtok = tok < n_tok ? tok : n_tok - 1;
    const float cth = cosf(theta[0]);
    const f32x4* xv = (const f32x4*)(x + (size_t)rtok * 8);
    f32x4 x0 = xv[0], x1 = xv[1];
    float q[8];
    q[0]=cth*cosf(x0.x); q[1]=cth*cosf(x0.y); q[2]=cth*cosf(x0.z); q[3]=cth*cosf(x0.w);
    q[4]=cth*cosf(x1.x); q[5]=cth*cosf(x1.y); q[6]=cth*cosf(x1.z); q[7]=cth*cosf(x1.w);
    float acc[8];
    #pragma unroll
    for (int e = 0; e < 8; ++e) acc[e] = 0.0f;
    const int f0 = wave * (FFN_DIM / 4), f1 = f0 + (FFN_DIM / 4);
    #pragma unroll 2
    for (int f = f0; f < f1; ++f) {
        const f32x4* w1r = (const f32x4*)(w1 + (size_t)f * 8);
        f32x4 u0 = w1r[0], u1 = w1r[1];
        float h = b1[f];
        h = fmaf(u0.x,q[0],h); h = fmaf(u0.y,q[1],h); h = fmaf(u0.z,q[2],h); h = fmaf(u0.w,q[3],h);
        h = fmaf(u1.x,q[4],h); h = fmaf(u1.y,q[5],h); h = fmaf(u1.z,q[6],h); h = fmaf(u1.w,q[7],h);
        h = fmaxf(h, 0.0f);
        #pragma unroll
        for (int e = 0; e < 8; ++e) acc[e] = fmaf(h, w2[e * FFN_DIM + f], acc[e]);
    }
    #pragma unroll
    for (int e = 0; e < 8; ++e) part[wave][lane][e] = acc[e];
    __syncthreads();
    for (int i = tid; i < 64 * 8; i += 256) {
        int t = i >> 3, e = i & 7;
        int gt = blockIdx.x * 64 + t;
        if (gt < n_tok)
            out[(size_t)gt * 8 + e] = part[0][t][e] + part[1][t][e]
                                    + part[2][t][e] + part[3][t][e] + b2[e];
    }
}

extern "C" void kernel_launch(void* const* d_in, const int* in_sizes, int n_in,
                              void* d_out, int out_size, void* d_ws, size_t ws_size,
                              hipStream_t stream) {
    const float* x     = (const float*)d_in[0];
    const float* theta = (const float*)d_in[1];
    const float* w1    = (const float*)d_in[2];
    const float* b1    = (const float*)d_in[3];
    const float* w2    = (const float*)d_in[4];
    const float* b2    = (const float*)d_in[5];
    float* out = (float*)d_out;
    const int n_tok = out_size / 8;

    const size_t W1F_BYTES = (size_t)NCHUNK * 64 * 8 * sizeof(_Float16);   // 128KB
    const size_t W2F_BYTES = (size_t)NCHUNK * 2 * 16 * 8 * sizeof(_Float16); // 64KB

    if (ws_size >= W1F_BYTES + W2F_BYTES) {
        _Float16* w1f = (_Float16*)d_ws;
        _Float16* w2f = (_Float16*)((char*)d_ws + W1F_BYTES);
        build_frags_kernel<<<(NCHUNK * 64 * 8 + 255) / 256, 256, 0, stream>>>(
            w1, b1, w2, w1f, w2f);
        int blocks = (n_tok + 127) / 128;   // four 32-token tiles per block
        ffq_mfma_kernel<<<blocks, 256, 0, stream>>>(x, theta, w1f, w2f, b2, out,
                                                    n_tok);
    } else {
        int grid = (n_tok + 63) / 64;
        ffq_valu_kernel<<<grid, 256, 0, stream>>>(x, theta, w1, b1, w2, b2, out,
                                                  n_tok);
    }
}